// Round 5
// baseline (1259.496 us; speedup 1.0000x reference)
//
#include <hip/hip_runtime.h>

#define BT (256*512)   // 131072 positions
#define HID 128
#define EMB 64
#define NB  16         // scan blocks
#define SEQ 16         // sequences per scan block

typedef _Float16 f16x4 __attribute__((ext_vector_type(4)));
typedef _Float16 f16x8 __attribute__((ext_vector_type(8)));
typedef float    f32x4 __attribute__((ext_vector_type(4)));

#define MFMA(a, b, c) __builtin_amdgcn_mfma_f32_16x16x32_f16(a, b, c, 0, 0, 0)
#define SHUF8(x, y) __builtin_shufflevector(x, y, 0, 1, 2, 3, 4, 5, 6, 7)
// LDS transpose-read: lane must pass base + lane*8 (bytes); elem j of lane l
// then holds lds16[base/2 + (l&15) + j*16 + (l>>4)*64]  (m156/m162 layout)
#define TRRD(dst, a, OFF) asm volatile("ds_read_b64_tr_b16 %0, %1 offset:" OFF : "=v"(dst) : "v"(a))
#define LDSR128(dst, a)   asm volatile("ds_read_b128 %0, %1" : "=v"(dst) : "v"(a))

__device__ __forceinline__ float fast_tanh(float x) {   // 1 - 2/(exp(2x)+1)
    float e = __expf(2.f * x);
    return 1.f - __fdividef(2.f, e + 1.f);
}

__device__ __forceinline__ unsigned ldsoff(const void* p) {
    return (unsigned)(unsigned long long)p;   // low 32 bits of generic addr = LDS offset
}

// ---------------- kernel 1: embedding gather + layer-1 input GEMM.
// Unchanged math; output layout changed to [t][b][h] for the batched scan.
__global__ __launch_bounds__(256)
__attribute__((amdgpu_waves_per_eu(1, 2)))
void k_embed_pre1(
    const int* __restrict__ x, const float* __restrict__ emb,
    const float* __restrict__ Wih1, const float* __restrict__ bih1,
    const float* __restrict__ bhh1, float* __restrict__ pre1)
{
    __shared__ float sA[32][128];
    __shared__ float sW[32][132];
    __shared__ int stok[128];
    const int tid = threadIdx.x;
    const int base = blockIdx.x * 128;
    const int tx = tid & 15, ty = tid >> 4;
    const int ox = tx * 8, py = ty * 8;
    const int pl = tid & 127, half = tid >> 7;
    if (tid < 128) stok[tid] = x[base + tid];
    float acc[8][8];
#pragma unroll
    for (int p = 0; p < 8; ++p)
#pragma unroll
        for (int o = 0; o < 8; ++o) acc[p][o] = 0.f;
    __syncthreads();
    const float4* ws = (const float4*)(Wih1 + (size_t)pl * EMB + half * 16);
    const float4* as = (const float4*)(emb + (size_t)stok[pl] * EMB + half * 16);
    float4 qw[2][4], qe[2][4];
#pragma unroll
    for (int kc = 0; kc < 2; ++kc)
#pragma unroll
        for (int k = 0; k < 4; ++k) {
            qw[kc][k] = ws[kc * 8 + k];
            qe[kc][k] = as[kc * 8 + k];
        }
    for (int kc = 0; kc < 2; ++kc) {
        {
            const int jb = half * 16;
#pragma unroll
            for (int k = 0; k < 4; ++k) {
                float4 q = qw[kc][k], e = qe[kc][k];
                sW[jb + 4*k + 0][pl] = q.x; sW[jb + 4*k + 1][pl] = q.y;
                sW[jb + 4*k + 2][pl] = q.z; sW[jb + 4*k + 3][pl] = q.w;
                sA[jb + 4*k + 0][pl] = e.x; sA[jb + 4*k + 1][pl] = e.y;
                sA[jb + 4*k + 2][pl] = e.z; sA[jb + 4*k + 3][pl] = e.w;
            }
        }
        __syncthreads();
#pragma unroll 4
        for (int j = 0; j < 32; ++j) {
            float4 a0 = *(const float4*)&sA[j][py];
            float4 a1 = *(const float4*)&sA[j][py + 4];
            float4 b0 = *(const float4*)&sW[j][ox];
            float4 b1 = *(const float4*)&sW[j][ox + 4];
            float av[8] = {a0.x,a0.y,a0.z,a0.w,a1.x,a1.y,a1.z,a1.w};
            float bv[8] = {b0.x,b0.y,b0.z,b0.w,b1.x,b1.y,b1.z,b1.w};
#pragma unroll
            for (int p = 0; p < 8; ++p)
#pragma unroll
                for (int o = 0; o < 8; ++o)
                    acc[p][o] = fmaf(av[p], bv[o], acc[p][o]);
        }
        __syncthreads();
    }
    float bo[8];
#pragma unroll
    for (int o = 0; o < 8; ++o) bo[o] = bih1[ox + o] + bhh1[ox + o];
#pragma unroll
    for (int p = 0; p < 8; ++p) {
        const int pos = base + py + p;
        const int bI = pos >> 9, tI = pos & 511;
        float* cp = pre1 + ((size_t)tI * 256 + bI) * HID + ox;
        *(float4*)cp       = make_float4(acc[p][0]+bo[0], acc[p][1]+bo[1], acc[p][2]+bo[2], acc[p][3]+bo[3]);
        *(float4*)(cp + 4) = make_float4(acc[p][4]+bo[4], acc[p][5]+bo[5], acc[p][6]+bo[6], acc[p][7]+bo[7]);
    }
}

// ---------------- kernel 2: batched two-layer recurrence, MFMA hi/lo form.
// 16 blocks x 16 seqs. A rows = sequences (full MFMA utilization). Weights as
// fp16 hi/lo B-fragments in registers (read natively by MFMA). 3-term product
// Whi@hhi + Whi@hlo + Wlo@hhi in fp32 accumulators => ~fp32 numerics.
// Waves: 0-1 L1 (Whh1), 2-3 IH2 (Wih2 -> P partial), 4-5 HH2 (Whh2 + P + b2).
// Lag pipeline (1 barrier/step): at step t publish h1_t, P_t = Wih2@h1_{t-1},
// h2_{t-2} = tanh(b2 + P_{t-1} + Whh2@h2_{t-3}).
__global__ __launch_bounds__(384)
__attribute__((amdgpu_waves_per_eu(2)))
void k_rnn_scan(
    const float* __restrict__ pre1T, const float* __restrict__ Whh1,
    const float* __restrict__ Wih2, const float* __restrict__ bih2,
    const float* __restrict__ bhh2, const float* __restrict__ Whh2,
    float* __restrict__ h2fin)
{
    // state tiles, [parity][arr: h1hi,h1lo,h2hi,h2lo][k*16 + seq] fp16 (tr-read layout)
    __shared__ __align__(16) _Float16 hT[2][4][HID * SEQ];
    __shared__ __align__(16) float    Pp[2][HID * SEQ];   // ih2 partials [out*16+seq]

    const int tid  = threadIdx.x;
    const int w    = tid >> 6, lane = tid & 63;
    const int role = w >> 1, half = w & 1;     // 0=L1, 1=IH2, 2=HH2
    const int col  = lane & 15;                // out-within-tile / B col
    const int kg   = lane >> 4;
    const int sb   = kg * 4;                   // seq base of this lane's D regs
    const int b0   = blockIdx.x * SEQ;

    {   // zero parity-0 state
        _Float16* z = &hT[0][0][0];
        for (int i = tid; i < 4 * HID * SEQ; i += 384) z[i] = (_Float16)0.f;
        for (int i = tid; i < HID * SEQ; i += 384) Pp[0][i] = 0.f;
    }

    // ---- weight fragments (fp16 hi/lo), 4 jobs x 4 ktiles, loaded once.
    // B-frag elem j of lane: j<4 -> k = kt*32 + kg*4 + j ; j>=4 -> +16 (matches A)
    const float* WM = (role == 0) ? Whh1 : ((role == 1) ? Wih2 : Whh2);
    f16x8 bh[4][4], bl[4][4];
    int outj[4];
#pragma unroll
    for (int j = 0; j < 4; ++j) {
        const int out = (half * 4 + j) * 16 + col;
        outj[j] = out;
        const float* rp = WM + (size_t)out * HID + kg * 4;
#pragma unroll
        for (int kt = 0; kt < 4; ++kt) {
            float4 a = *(const float4*)(rp + kt * 32);
            float4 b4 = *(const float4*)(rp + kt * 32 + 16);
            float v[8] = {a.x, a.y, a.z, a.w, b4.x, b4.y, b4.z, b4.w};
            f16x8 hi, lo;
#pragma unroll
            for (int q = 0; q < 8; ++q) {
                _Float16 h = (_Float16)v[q];
                hi[q] = h;
                lo[q] = (_Float16)(v[q] - (float)h);
            }
            bh[j][kt] = hi; bl[j][kt] = lo;
        }
    }
    float b2j[4] = {0.f, 0.f, 0.f, 0.f};
    if (role == 2) {
#pragma unroll
        for (int j = 0; j < 4; ++j) b2j[j] = bih2[outj[j]] + bhh2[outj[j]];
    }

    // ---- tr-read base addresses (per parity), and P offsets
    const unsigned hTb = ldsoff(&hT[0][0][0]);
    const unsigned Ppb = ldsoff(&Pp[0][0]);
    const int arr = (role == 2) ? 2 : 0;
    const unsigned aHi0 = hTb + arr * 4096 + lane * 8;
    const unsigned aHi1 = aHi0 + 16384;
    int pjo[4];
#pragma unroll
    for (int j = 0; j < 4; ++j) pjo[j] = (outj[j] * 16 + sb) * 4;

    // ---- pre1 prefetch (L1 only): registers for step t
    float pc[4][4];
    if (role == 0) {
#pragma unroll
        for (int j = 0; j < 4; ++j)
#pragma unroll
            for (int r = 0; r < 4; ++r)
                pc[j][r] = pre1T[(size_t)(b0 + sb + r) * HID + outj[j]];
    }
    __syncthreads();

    auto stepf = [&](int t, int rp) {
        const int wp = rp ^ 1;
        if (role == 0) {                                   // ---- L1: h1_t
            if (t < 512) {
                const unsigned ah = rp ? aHi1 : aHi0;
                const unsigned al = ah + 4096;
                f16x4 u0,u1,u2,u3,u4,u5,u6,u7, m0,m1,m2,m3,m4,m5,m6,m7;
                TRRD(u0, ah, "0");    TRRD(u1, ah, "512");
                TRRD(u2, ah, "1024"); TRRD(u3, ah, "1536");
                TRRD(u4, ah, "2048"); TRRD(u5, ah, "2560");
                TRRD(u6, ah, "3072"); TRRD(u7, ah, "3584");
                TRRD(m0, al, "0");    TRRD(m1, al, "512");
                TRRD(m2, al, "1024"); TRRD(m3, al, "1536");
                TRRD(m4, al, "2048"); TRRD(m5, al, "2560");
                TRRD(m6, al, "3072"); TRRD(m7, al, "3584");
                asm volatile("s_waitcnt lgkmcnt(0)" ::: "memory");
                __builtin_amdgcn_sched_barrier(0);
                f16x8 Ah[4] = {SHUF8(u0,u1), SHUF8(u2,u3), SHUF8(u4,u5), SHUF8(u6,u7)};
                f16x8 Al[4] = {SHUF8(m0,m1), SHUF8(m2,m3), SHUF8(m4,m5), SHUF8(m6,m7)};
#pragma unroll
                for (int j = 0; j < 4; ++j) {
                    f32x4 c = {pc[j][0], pc[j][1], pc[j][2], pc[j][3]};
#pragma unroll
                    for (int kt = 0; kt < 4; ++kt) c = MFMA(Ah[kt], bh[j][kt], c);
#pragma unroll
                    for (int kt = 0; kt < 4; ++kt) c = MFMA(Al[kt], bh[j][kt], c);
#pragma unroll
                    for (int kt = 0; kt < 4; ++kt) c = MFMA(Ah[kt], bl[j][kt], c);
                    f16x4 hi4, lo4;
#pragma unroll
                    for (int r = 0; r < 4; ++r) {
                        float v = fast_tanh(c[r]);
                        _Float16 h = (_Float16)v;
                        hi4[r] = h;
                        lo4[r] = (_Float16)(v - (float)h);
                    }
                    *(f16x4*)&hT[wp][0][outj[j] * 16 + sb] = hi4;
                    *(f16x4*)&hT[wp][1][outj[j] * 16 + sb] = lo4;
                }
                const int tn = (t + 1 < 512) ? t + 1 : 511;   // prefetch next step
                const size_t tb = (size_t)tn * 256 + b0 + sb;
#pragma unroll
                for (int j = 0; j < 4; ++j)
#pragma unroll
                    for (int r = 0; r < 4; ++r)
                        pc[j][r] = pre1T[(tb + r) * HID + outj[j]];
            }
        } else if (role == 1) {                            // ---- IH2: P_t = Wih2@h1_{t-1}
            if (t < 513) {
                const unsigned ah = rp ? aHi1 : aHi0;
                const unsigned al = ah + 4096;
                f16x4 u0,u1,u2,u3,u4,u5,u6,u7, m0,m1,m2,m3,m4,m5,m6,m7;
                TRRD(u0, ah, "0");    TRRD(u1, ah, "512");
                TRRD(u2, ah, "1024"); TRRD(u3, ah, "1536");
                TRRD(u4, ah, "2048"); TRRD(u5, ah, "2560");
                TRRD(u6, ah, "3072"); TRRD(u7, ah, "3584");
                TRRD(m0, al, "0");    TRRD(m1, al, "512");
                TRRD(m2, al, "1024"); TRRD(m3, al, "1536");
                TRRD(m4, al, "2048"); TRRD(m5, al, "2560");
                TRRD(m6, al, "3072"); TRRD(m7, al, "3584");
                asm volatile("s_waitcnt lgkmcnt(0)" ::: "memory");
                __builtin_amdgcn_sched_barrier(0);
                f16x8 Ah[4] = {SHUF8(u0,u1), SHUF8(u2,u3), SHUF8(u4,u5), SHUF8(u6,u7)};
                f16x8 Al[4] = {SHUF8(m0,m1), SHUF8(m2,m3), SHUF8(m4,m5), SHUF8(m6,m7)};
#pragma unroll
                for (int j = 0; j < 4; ++j) {
                    f32x4 c = {0.f, 0.f, 0.f, 0.f};
#pragma unroll
                    for (int kt = 0; kt < 4; ++kt) c = MFMA(Ah[kt], bh[j][kt], c);
#pragma unroll
                    for (int kt = 0; kt < 4; ++kt) c = MFMA(Al[kt], bh[j][kt], c);
#pragma unroll
                    for (int kt = 0; kt < 4; ++kt) c = MFMA(Ah[kt], bl[j][kt], c);
                    *(f32x4*)&Pp[wp][outj[j] * 16 + sb] = c;
                }
            }
        } else {                                           // ---- HH2: h2_{t-2}
            const unsigned ah = rp ? aHi1 : aHi0;
            const unsigned al = ah + 4096;
            const unsigned pb = Ppb + rp * 8192;
            f32x4 P0, P1, P2, P3;
            LDSR128(P0, pb + pjo[0]); LDSR128(P1, pb + pjo[1]);
            LDSR128(P2, pb + pjo[2]); LDSR128(P3, pb + pjo[3]);
            f16x4 u0,u1,u2,u3,u4,u5,u6,u7, m0,m1,m2,m3,m4,m5,m6,m7;
            TRRD(u0, ah, "0");    TRRD(u1, ah, "512");
            TRRD(u2, ah, "1024"); TRRD(u3, ah, "1536");
            TRRD(u4, ah, "2048"); TRRD(u5, ah, "2560");
            TRRD(u6, ah, "3072"); TRRD(u7, ah, "3584");
            TRRD(m0, al, "0");    TRRD(m1, al, "512");
            TRRD(m2, al, "1024"); TRRD(m3, al, "1536");
            TRRD(m4, al, "2048"); TRRD(m5, al, "2560");
            TRRD(m6, al, "3072"); TRRD(m7, al, "3584");
            asm volatile("s_waitcnt lgkmcnt(0)" ::: "memory");
            __builtin_amdgcn_sched_barrier(0);
            f16x8 Ah[4] = {SHUF8(u0,u1), SHUF8(u2,u3), SHUF8(u4,u5), SHUF8(u6,u7)};
            f16x8 Al[4] = {SHUF8(m0,m1), SHUF8(m2,m3), SHUF8(m4,m5), SHUF8(m6,m7)};
            f32x4 Pj[4] = {P0, P1, P2, P3};
#pragma unroll
            for (int j = 0; j < 4; ++j) {
                f32x4 c;
#pragma unroll
                for (int r = 0; r < 4; ++r) c[r] = Pj[j][r] + b2j[j];
#pragma unroll
                for (int kt = 0; kt < 4; ++kt) c = MFMA(Ah[kt], bh[j][kt], c);
#pragma unroll
                for (int kt = 0; kt < 4; ++kt) c = MFMA(Al[kt], bh[j][kt], c);
#pragma unroll
                for (int kt = 0; kt < 4; ++kt) c = MFMA(Ah[kt], bl[j][kt], c);
                if (t < 513) {
                    f16x4 hi4, lo4;
#pragma unroll
                    for (int r = 0; r < 4; ++r) {
                        float v = (t >= 2) ? fast_tanh(c[r]) : 0.f;   // h2_{neg} = 0
                        _Float16 h = (_Float16)v;
                        hi4[r] = h;
                        lo4[r] = (_Float16)(v - (float)h);
                    }
                    *(f16x4*)&hT[wp][2][outj[j] * 16 + sb] = hi4;
                    *(f16x4*)&hT[wp][3][outj[j] * 16 + sb] = lo4;
                } else {                                   // t == 513: h2_511 -> global
#pragma unroll
                    for (int r = 0; r < 4; ++r)
                        h2fin[(size_t)(b0 + sb + r) * HID + outj[j]] = fast_tanh(c[r]);
                }
            }
        }
        __syncthreads();
    };

#pragma unroll 1
    for (int tt = 0; tt < 514; tt += 2) {
        stepf(tt, 0);
        stepf(tt + 1, 1);
    }
}

// ---------------- kernel 3: per-sequence head: LN -> proj+tanh -> LN
__global__ __launch_bounds__(128)
void k_head(const float* __restrict__ h2fin,
            const float* __restrict__ ln_g, const float* __restrict__ ln_b,
            const float* __restrict__ projW, const float* __restrict__ proj_b,
            const float* __restrict__ on_g, const float* __restrict__ on_b,
            float* __restrict__ out)
{
    __shared__ float xn[HID];
    __shared__ float red[4];
    const int b = blockIdx.x, i = threadIdx.x, wv = i >> 6;
    float v = h2fin[(size_t)b * HID + i];
    float sa = v, sq = v * v;
#pragma unroll
    for (int o = 32; o > 0; o >>= 1) { sa += __shfl_xor(sa, o, 64); sq += __shfl_xor(sq, o, 64); }
    if ((i & 63) == 0) { red[wv * 2] = sa; red[wv * 2 + 1] = sq; }
    __syncthreads();
    float S = red[0] + red[2], Q = red[1] + red[3];
    float mu = S * (1.f / 128.f), var = Q * (1.f / 128.f) - mu * mu;
    float rs = rsqrtf(var + 1e-5f);
    xn[i] = (v - mu) * rs * ln_g[i] + ln_b[i];
    __syncthreads();
    float a0 = proj_b[i], a1 = 0.f, a2 = 0.f, a3 = 0.f;
    const float4* pr = (const float4*)(projW + (size_t)i * HID);
    const float4* hp = (const float4*)xn;
#pragma unroll
    for (int k = 0; k < 32; ++k) {
        float4 u = pr[k], h4 = hp[k];
        a0 = fmaf(h4.x, u.x, a0); a1 = fmaf(h4.y, u.y, a1);
        a2 = fmaf(h4.z, u.z, a2); a3 = fmaf(h4.w, u.w, a3);
    }
    float pv = tanhf((a0 + a1) + (a2 + a3));
    float ta = pv, tq = pv * pv;
#pragma unroll
    for (int o = 32; o > 0; o >>= 1) { ta += __shfl_xor(ta, o, 64); tq += __shfl_xor(tq, o, 64); }
    __syncthreads();
    if ((i & 63) == 0) { red[wv * 2] = ta; red[wv * 2 + 1] = tq; }
    __syncthreads();
    float S2 = red[0] + red[2], Q2 = red[1] + red[3];
    float mu2 = S2 * (1.f / 128.f), var2 = Q2 * (1.f / 128.f) - mu2 * mu2;
    float rs2 = rsqrtf(var2 + 1e-5f);
    out[(size_t)b * HID + i] = (pv - mu2) * rs2 * on_g[i] + on_b[i];
}

extern "C" void kernel_launch(void* const* d_in, const int* in_sizes, int n_in,
                              void* d_out, int out_size, void* d_ws, size_t ws_size,
                              hipStream_t stream)
{
    const int*   x     = (const int*)  d_in[0];
    const float* emb   = (const float*)d_in[1];
    const float* Wih1  = (const float*)d_in[2];
    const float* bih1  = (const float*)d_in[3];
    const float* Whh1  = (const float*)d_in[4];
    const float* bhh1  = (const float*)d_in[5];
    const float* Wih2  = (const float*)d_in[6];
    const float* bih2  = (const float*)d_in[7];
    const float* Whh2  = (const float*)d_in[8];
    const float* bhh2  = (const float*)d_in[9];
    const float* ln_g  = (const float*)d_in[10];
    const float* ln_b  = (const float*)d_in[11];
    const float* projW = (const float*)d_in[12];
    const float* projb = (const float*)d_in[13];
    const float* on_g  = (const float*)d_in[14];
    const float* on_b  = (const float*)d_in[15];

    float* pre1  = (float*)d_ws;                            // [512][256][128] fp32, t-major
    float* h2fin = pre1 + (size_t)511 * 256 * HID;          // reuses consumed t=511 slab

    k_embed_pre1<<<BT / 128, 256, 0, stream>>>(x, emb, Wih1, bih1, bhh1, pre1);
    k_rnn_scan<<<NB, 384, 0, stream>>>(pre1, Whh1, Wih2, bih2, bhh2, Whh2, h2fin);
    k_head<<<256, 128, 0, stream>>>(h2fin, ln_g, ln_b, projW, projb, on_g, on_b,
                                    (float*)d_out);
}

// Round 6
// 622.690 us; speedup vs baseline: 2.0227x; 2.0227x over previous
//
#include <hip/hip_runtime.h>

#define BT (256*512)   // 131072 positions
#define HID 128
#define EMB 64
#define CH 32          // scan chunk: steps staged per LDS refill

typedef _Float16 f16x8 __attribute__((ext_vector_type(8)));
typedef float    f32x4 __attribute__((ext_vector_type(4)));
#define MFMA(a, b, c) __builtin_amdgcn_mfma_f32_16x16x32_f16(a, b, c, 0, 0, 0)

__device__ __forceinline__ float fast_tanh(float x) {   // 1 - 2/(exp(2x)+1)
    float e = __expf(2.f * x);
    return 1.f - __fdividef(2.f, e + 1.f);
}

// ---------------- kernel 1: embedding gather + layer-1 input GEMM (round-3 exact)
__global__ __launch_bounds__(256)
__attribute__((amdgpu_waves_per_eu(1, 2)))
void k_embed_pre1(
    const int* __restrict__ x, const float* __restrict__ emb,
    const float* __restrict__ Wih1, const float* __restrict__ bih1,
    const float* __restrict__ bhh1, float* __restrict__ pre1)
{
    __shared__ float sA[32][128];
    __shared__ float sW[32][132];
    __shared__ int stok[128];
    const int tid = threadIdx.x;
    const int base = blockIdx.x * 128;
    const int tx = tid & 15, ty = tid >> 4;
    const int ox = tx * 8, py = ty * 8;
    const int pl = tid & 127, half = tid >> 7;
    if (tid < 128) stok[tid] = x[base + tid];
    float acc[8][8];
#pragma unroll
    for (int p = 0; p < 8; ++p)
#pragma unroll
        for (int o = 0; o < 8; ++o) acc[p][o] = 0.f;
    __syncthreads();
    const float4* ws = (const float4*)(Wih1 + (size_t)pl * EMB + half * 16);
    const float4* as = (const float4*)(emb + (size_t)stok[pl] * EMB + half * 16);
    float4 qw[2][4], qe[2][4];
#pragma unroll
    for (int kc = 0; kc < 2; ++kc)
#pragma unroll
        for (int k = 0; k < 4; ++k) {
            qw[kc][k] = ws[kc * 8 + k];
            qe[kc][k] = as[kc * 8 + k];
        }
    for (int kc = 0; kc < 2; ++kc) {
        {
            const int jb = half * 16;
#pragma unroll
            for (int k = 0; k < 4; ++k) {
                float4 q = qw[kc][k], e = qe[kc][k];
                sW[jb + 4*k + 0][pl] = q.x; sW[jb + 4*k + 1][pl] = q.y;
                sW[jb + 4*k + 2][pl] = q.z; sW[jb + 4*k + 3][pl] = q.w;
                sA[jb + 4*k + 0][pl] = e.x; sA[jb + 4*k + 1][pl] = e.y;
                sA[jb + 4*k + 2][pl] = e.z; sA[jb + 4*k + 3][pl] = e.w;
            }
        }
        __syncthreads();
#pragma unroll 4
        for (int j = 0; j < 32; ++j) {
            float4 a0 = *(const float4*)&sA[j][py];
            float4 a1 = *(const float4*)&sA[j][py + 4];
            float4 b0 = *(const float4*)&sW[j][ox];
            float4 b1 = *(const float4*)&sW[j][ox + 4];
            float av[8] = {a0.x,a0.y,a0.z,a0.w,a1.x,a1.y,a1.z,a1.w};
            float bv[8] = {b0.x,b0.y,b0.z,b0.w,b1.x,b1.y,b1.z,b1.w};
#pragma unroll
            for (int p = 0; p < 8; ++p)
#pragma unroll
                for (int o = 0; o < 8; ++o)
                    acc[p][o] = fmaf(av[p], bv[o], acc[p][o]);
        }
        __syncthreads();
    }
    float bo[8];
#pragma unroll
    for (int o = 0; o < 8; ++o) bo[o] = bih1[ox + o] + bhh1[ox + o];
#pragma unroll
    for (int p = 0; p < 8; ++p) {
        float* cp = pre1 + (size_t)(base + py + p) * HID + ox;
        *(float4*)cp       = make_float4(acc[p][0]+bo[0], acc[p][1]+bo[1], acc[p][2]+bo[2], acc[p][3]+bo[3]);
        *(float4*)(cp + 4) = make_float4(acc[p][4]+bo[4], acc[p][5]+bo[5], acc[p][6]+bo[6], acc[p][7]+bo[7]);
    }
}

// block-wide sum for 768 threads (12 waves); pass 0 from non-contributing lanes
__device__ inline float bsum768(float v, volatile float* sc, int tid) {
#pragma unroll
    for (int off = 32; off > 0; off >>= 1) v += __shfl_down(v, off, 64);
    __syncthreads();
    if ((tid & 63) == 0) sc[tid >> 6] = v;
    __syncthreads();
    float s = 0.f;
#pragma unroll
    for (int k = 0; k < 12; ++k) s += sc[k];
    return s;
}

// ---------------- kernel 2: fused two-layer recurrence, broadcast-A MFMA hi/lo.
// 256 blocks x 1 seq, 12 waves. A = h broadcast across all 16 MFMA rows (row-
// uniform A => row-uniform D => lane's value is its col, mapping-immune; A/B use
// IDENTICAL slot->index maps so any true layout cancels). Weights = fp16 hi/lo
// B-fragments resident in the unified VGPR/AGPR file, read natively by MFMA
// (kills the AGPR-copy tax of the VALU versions). Precision via 3-term
// Whi@hhi + Whi@hlo + Wlo@hhi, fp32 accum (round-5-proven: absmax 0.0078).
// Roles (4 waves each), lag-1 pipeline (round-5-proven), 1 barrier/step:
//   L1 : h1_t    = tanh(pre1[t] + Whh1 @ h1_{t-1})        (C-init = pre1)
//   IH2: P_t     = Wih2 @ h1_{t-1}                        (published to Pp)
//   HH2: h2_{t-2} = tanh(b2 + P_{t-1} + Whh2 @ h2_{t-3})  (C-init = P + b2)
__global__ __launch_bounds__(768)
__attribute__((amdgpu_waves_per_eu(3)))
void k_rnn_fused(
    const float* __restrict__ pre1, const float* __restrict__ Whh1,
    const float* __restrict__ Wih2, const float* __restrict__ bih2,
    const float* __restrict__ bhh2, const float* __restrict__ Whh2,
    const float* __restrict__ ln_g, const float* __restrict__ ln_b,
    const float* __restrict__ projW, const float* __restrict__ proj_b,
    const float* __restrict__ on_g, const float* __restrict__ on_b,
    float* __restrict__ out)
{
    __shared__ __align__(16) _Float16 h1h[2][HID], h1l[2][HID];  // h1 hi/lo, parity dbuf
    __shared__ __align__(16) _Float16 h2h[2][HID], h2l[2][HID];  // h2 hi/lo
    __shared__ __align__(16) float    Pp[2][HID];                // Wih2@h1 partials
    __shared__ __align__(16) float    spre[CH * HID];            // staged pre1 (16 KB)
    __shared__ float sfin[HID];
    __shared__ float sc[12];

    const int bb   = blockIdx.x;
    const int tid  = threadIdx.x;
    const int w    = tid >> 6, lane = tid & 63;
    const int role = w >> 2;               // 0=L1, 1=IH2, 2=HH2
    const int tw   = w & 3;                // out-tile pair index within role
    const int col  = lane & 15;            // B col = D col = output within tile
    const int kg   = lane >> 4;            // k-group: frag slot (kg,j) <-> k = kg*8+j
    const int out0 = (2 * tw) * 16 + col;
    const int out1 = (2 * tw + 1) * 16 + col;

    // ---- weight B-fragments, fp16 hi/lo, loaded once (16 frags = 64 VGPR)
    const float* WM = (role == 0) ? Whh1 : ((role == 1) ? Wih2 : Whh2);
    f16x8 bh[2][4], bl[2][4];
#pragma unroll
    for (int j = 0; j < 2; ++j) {
        const int oj = j ? out1 : out0;
        const float* rw = WM + (size_t)oj * HID + kg * 8;
#pragma unroll
        for (int kt = 0; kt < 4; ++kt) {
            float4 u0 = *(const float4*)(rw + kt * 32);
            float4 u1 = *(const float4*)(rw + kt * 32 + 4);
            float vv[8] = {u0.x,u0.y,u0.z,u0.w,u1.x,u1.y,u1.z,u1.w};
            f16x8 hi, lo;
#pragma unroll
            for (int q = 0; q < 8; ++q) {
                _Float16 hq = (_Float16)vv[q];
                hi[q] = hq;
                lo[q] = (_Float16)(vv[q] - (float)hq);
            }
            bh[j][kt] = hi; bl[j][kt] = lo;
        }
    }
    float b20 = 0.f, b21 = 0.f;
    if (role == 2) {
        b20 = bih2[out0] + bhh2[out0];
        b21 = bih2[out1] + bhh2[out1];
    }

    if (tid < 128) {
        h1h[0][tid] = (_Float16)0.f; h1l[0][tid] = (_Float16)0.f;
        h2h[0][tid] = (_Float16)0.f; h2l[0][tid] = (_Float16)0.f;
        Pp[0][tid] = 0.f;
    }

    // parity-resolved A-source bases (wave-uniform)
    const f16x8* A0h = (role == 2) ? (const f16x8*)h2h[0] : (const f16x8*)h1h[0];
    const f16x8* A0l = (role == 2) ? (const f16x8*)h2l[0] : (const f16x8*)h1l[0];
    const f16x8* A1h = (role == 2) ? (const f16x8*)h2h[1] : (const f16x8*)h1h[1];
    const f16x8* A1l = (role == 2) ? (const f16x8*)h2l[1] : (const f16x8*)h1l[1];

    const float4* gsrc = (const float4*)(pre1 + (size_t)bb * 512 * HID);
    float4* spv = (float4*)spre;
    float4 pf0, pf1;
    if (tid < 512) { pf0 = gsrc[tid]; pf1 = gsrc[tid + 512]; }
    __syncthreads();                    // h init visible

    auto stepf = [&](int t, int rp, int s) {
        const int wp = rp ^ 1;
        const bool active = (role == 0) ? (t < 512) : ((role == 1) ? (t < 513) : true);
        if (active) {
            const f16x8* Ah = rp ? A1h : A0h;
            const f16x8* Al = rp ? A1l : A0l;
            f16x8 ah0 = Ah[kg], ah1 = Ah[4 + kg], ah2 = Ah[8 + kg], ah3 = Ah[12 + kg];
            f16x8 al0 = Al[kg], al1 = Al[4 + kg], al2 = Al[8 + kg], al3 = Al[12 + kg];
            float i0, i1;
            if (role == 0)      { i0 = spre[s * HID + out0]; i1 = spre[s * HID + out1]; }
            else if (role == 1) { i0 = 0.f; i1 = 0.f; }
            else                { i0 = Pp[rp][out0] + b20; i1 = Pp[rp][out1] + b21; }
            f32x4 cA0 = {i0,i0,i0,i0}, cB0 = {0,0,0,0}, cC0 = {0,0,0,0};
            f32x4 cA1 = {i1,i1,i1,i1}, cB1 = {0,0,0,0}, cC1 = {0,0,0,0};
            // 6 independent 4-deep chains (issue distance >> MFMA latency)
            cA0 = MFMA(ah0, bh[0][0], cA0); cA1 = MFMA(ah0, bh[1][0], cA1);
            cB0 = MFMA(al0, bh[0][0], cB0); cB1 = MFMA(al0, bh[1][0], cB1);
            cC0 = MFMA(ah0, bl[0][0], cC0); cC1 = MFMA(ah0, bl[1][0], cC1);
            cA0 = MFMA(ah1, bh[0][1], cA0); cA1 = MFMA(ah1, bh[1][1], cA1);
            cB0 = MFMA(al1, bh[0][1], cB0); cB1 = MFMA(al1, bh[1][1], cB1);
            cC0 = MFMA(ah1, bl[0][1], cC0); cC1 = MFMA(ah1, bl[1][1], cC1);
            cA0 = MFMA(ah2, bh[0][2], cA0); cA1 = MFMA(ah2, bh[1][2], cA1);
            cB0 = MFMA(al2, bh[0][2], cB0); cB1 = MFMA(al2, bh[1][2], cB1);
            cC0 = MFMA(ah2, bl[0][2], cC0); cC1 = MFMA(ah2, bl[1][2], cC1);
            cA0 = MFMA(ah3, bh[0][3], cA0); cA1 = MFMA(ah3, bh[1][3], cA1);
            cB0 = MFMA(al3, bh[0][3], cB0); cB1 = MFMA(al3, bh[1][3], cB1);
            cC0 = MFMA(ah3, bl[0][3], cC0); cC1 = MFMA(ah3, bl[1][3], cC1);
            float v0 = (cA0[0] + cB0[0]) + cC0[0];
            float v1 = (cA1[0] + cB1[0]) + cC1[0];
            if (role == 0) {
                float q0 = fast_tanh(v0), q1 = fast_tanh(v1);
                _Float16 H0 = (_Float16)q0, H1 = (_Float16)q1;
                _Float16 L0 = (_Float16)(q0 - (float)H0);
                _Float16 L1 = (_Float16)(q1 - (float)H1);
                if (kg == 0) {
                    h1h[wp][out0] = H0; h1l[wp][out0] = L0;
                    h1h[wp][out1] = H1; h1l[wp][out1] = L1;
                }
            } else if (role == 1) {
                if (kg == 0) { Pp[wp][out0] = v0; Pp[wp][out1] = v1; }
            } else {
                if (t < 513) {
                    float q0 = (t >= 2) ? fast_tanh(v0) : 0.f;   // h2_{neg} = 0
                    float q1 = (t >= 2) ? fast_tanh(v1) : 0.f;
                    _Float16 H0 = (_Float16)q0, H1 = (_Float16)q1;
                    _Float16 L0 = (_Float16)(q0 - (float)H0);
                    _Float16 L1 = (_Float16)(q1 - (float)H1);
                    if (kg == 0) {
                        h2h[wp][out0] = H0; h2l[wp][out0] = L0;
                        h2h[wp][out1] = H1; h2l[wp][out1] = L1;
                    }
                } else if (kg == 0) {                            // t == 513: h2_511
                    sfin[out0] = fast_tanh(v0);
                    sfin[out1] = fast_tanh(v1);
                }
            }
        }
        __syncthreads();
    };

#pragma unroll 1
    for (int c = 0; c < 512 / CH; ++c) {
        if (tid < 512) { spv[tid] = pf0; spv[tid + 512] = pf1; }
        __syncthreads();
        if (c < 512 / CH - 1 && tid < 512) {   // prefetch next chunk under 32 steps
            pf0 = gsrc[(c + 1) * 1024 + tid];
            pf1 = gsrc[(c + 1) * 1024 + tid + 512];
        }
        const int t0 = c * CH;
#pragma unroll 1
        for (int s = 0; s < CH; s += 2) {
            stepf(t0 + s,     0, s);
            stepf(t0 + s + 1, 1, s + 1);
        }
    }
    // drain: t=512 (IH2 publishes P_512, HH2 h2_510), t=513 (HH2 -> sfin = h2_511)
    stepf(512, 0, 0);
    stepf(513, 1, 0);

    // ---- epilogue: LN -> proj+tanh -> LN (round-3 exact)
    const int i = tid & 127;
    float hn = (tid < 128) ? sfin[i] : 0.f;
    float s1v = bsum768(hn, sc, tid);
    float s2v = bsum768(hn * hn, sc, tid);
    float mu = s1v * (1.f / 128.f);
    float var = s2v * (1.f / 128.f) - mu * mu;
    __syncthreads();
    if (tid < 128) spre[i] = (hn - mu) * rsqrtf(var + 1e-5f) * ln_g[i] + ln_b[i];
    __syncthreads();
    float pv = 0.f;
    if (tid < 128) {
        float a0 = proj_b[i], a1 = 0, a2 = 0, a3 = 0;
        const float4* hp = (const float4*)spre;
        const float4* pr = (const float4*)(projW + (size_t)i * HID);
#pragma unroll
        for (int k = 0; k < HID / 4; ++k) {
            float4 u = pr[k];
            float4 hv = hp[k];
            a0 = fmaf(hv.x, u.x, a0); a1 = fmaf(hv.y, u.y, a1);
            a2 = fmaf(hv.z, u.z, a2); a3 = fmaf(hv.w, u.w, a3);
        }
        pv = tanhf((a0 + a1) + (a2 + a3));
    }
    float t1 = bsum768(pv, sc, tid);
    float t2 = bsum768(pv * pv, sc, tid);
    float mu2 = t1 * (1.f / 128.f);
    float var2 = t2 * (1.f / 128.f) - mu2 * mu2;
    if (tid < 128)
        out[(size_t)bb * HID + i] = (pv - mu2) * rsqrtf(var2 + 1e-5f) * on_g[i] + on_b[i];
}

extern "C" void kernel_launch(void* const* d_in, const int* in_sizes, int n_in,
                              void* d_out, int out_size, void* d_ws, size_t ws_size,
                              hipStream_t stream)
{
    const int*   x     = (const int*)  d_in[0];
    const float* emb   = (const float*)d_in[1];
    const float* Wih1  = (const float*)d_in[2];
    const float* bih1  = (const float*)d_in[3];
    const float* Whh1  = (const float*)d_in[4];
    const float* bhh1  = (const float*)d_in[5];
    const float* Wih2  = (const float*)d_in[6];
    const float* bih2  = (const float*)d_in[7];
    const float* Whh2  = (const float*)d_in[8];
    const float* bhh2  = (const float*)d_in[9];
    const float* ln_g  = (const float*)d_in[10];
    const float* ln_b  = (const float*)d_in[11];
    const float* projW = (const float*)d_in[12];
    const float* projb = (const float*)d_in[13];
    const float* on_g  = (const float*)d_in[14];
    const float* on_b  = (const float*)d_in[15];

    float* pre1 = (float*)d_ws;   // 64 MiB fp32

    k_embed_pre1<<<BT / 128, 256, 0, stream>>>(x, emb, Wih1, bih1, bhh1, pre1);
    k_rnn_fused<<<256, 768, 0, stream>>>(pre1, Whh1, Wih2, bih2, bhh2, Whh2,
                                         ln_g, ln_b, projW, projb, on_g, on_b,
                                         (float*)d_out);
}

// Round 8
// 471.210 us; speedup vs baseline: 2.6729x; 1.3215x over previous
//
#include <hip/hip_runtime.h>

#define BT (256*512)   // 131072 positions
#define HID 128
#define EMB 64

__device__ __forceinline__ float fast_tanh(float x) {   // 1 - 2/(exp(2x)+1)
    float e = __expf(2.f * x);
    return 1.f - __fdividef(2.f, e + 1.f);
}

#define OPQ(v) asm volatile("" : "+v"(v.x), "+v"(v.y), "+v"(v.z), "+v"(v.w))

// 16-wide dot of one h-slice (4 float4) against one weight row slice (4 float4)
#define DOT16(d, A0, A1, A2, A3, WJ) \
    d = A0.x*WJ[0].x; d = fmaf(A0.y, WJ[0].y, d); d = fmaf(A0.z, WJ[0].z, d); d = fmaf(A0.w, WJ[0].w, d); \
    d = fmaf(A1.x, WJ[1].x, d); d = fmaf(A1.y, WJ[1].y, d); d = fmaf(A1.z, WJ[1].z, d); d = fmaf(A1.w, WJ[1].w, d); \
    d = fmaf(A2.x, WJ[2].x, d); d = fmaf(A2.y, WJ[2].y, d); d = fmaf(A2.z, WJ[2].z, d); d = fmaf(A2.w, WJ[2].w, d); \
    d = fmaf(A3.x, WJ[3].x, d); d = fmaf(A3.y, WJ[3].y, d); d = fmaf(A3.z, WJ[3].z, d); d = fmaf(A3.w, WJ[3].w, d);

// fused DPP butterfly reduce over the 8 column-eighths (lanes e=lane&7):
// xor1, xor2, then half-mirror (7-e; valid since quad-sums are replicated).
// Proven in R2/R3 (absmax 0.0078). 6 values, dependent ops 6 apart.
#define RSTG6(ctrl) \
    "v_add_f32_dpp %0, %0, %0 " ctrl " row_mask:0xf bank_mask:0xf\n\t" \
    "v_add_f32_dpp %1, %1, %1 " ctrl " row_mask:0xf bank_mask:0xf\n\t" \
    "v_add_f32_dpp %2, %2, %2 " ctrl " row_mask:0xf bank_mask:0xf\n\t" \
    "v_add_f32_dpp %3, %3, %3 " ctrl " row_mask:0xf bank_mask:0xf\n\t" \
    "v_add_f32_dpp %4, %4, %4 " ctrl " row_mask:0xf bank_mask:0xf\n\t" \
    "v_add_f32_dpp %5, %5, %5 " ctrl " row_mask:0xf bank_mask:0xf\n\t"
#define REDUCE6 asm("s_nop 1\n\t" \
    RSTG6("quad_perm:[1,0,3,2]") \
    RSTG6("quad_perm:[2,3,0,1]") \
    RSTG6("row_half_mirror") \
    : "+v"(s0), "+v"(s1), "+v"(s2), "+v"(s3), "+v"(s4), "+v"(s5))

// ---------------- kernel 1: embedding gather + layer-1 input GEMM (proven, unchanged)
__global__ __launch_bounds__(256)
__attribute__((amdgpu_waves_per_eu(1, 2)))
void k_embed_pre1(
    const int* __restrict__ x, const float* __restrict__ emb,
    const float* __restrict__ Wih1, const float* __restrict__ bih1,
    const float* __restrict__ bhh1, float* __restrict__ pre1)
{
    __shared__ float sA[32][128];
    __shared__ float sW[32][132];
    __shared__ int stok[128];
    const int tid = threadIdx.x;
    const int base = blockIdx.x * 128;
    const int tx = tid & 15, ty = tid >> 4;
    const int ox = tx * 8, py = ty * 8;
    const int pl = tid & 127, half = tid >> 7;
    if (tid < 128) stok[tid] = x[base + tid];
    float acc[8][8];
#pragma unroll
    for (int p = 0; p < 8; ++p)
#pragma unroll
        for (int o = 0; o < 8; ++o) acc[p][o] = 0.f;
    __syncthreads();
    const float4* ws = (const float4*)(Wih1 + (size_t)pl * EMB + half * 16);
    const float4* as = (const float4*)(emb + (size_t)stok[pl] * EMB + half * 16);
    float4 qw[2][4], qe[2][4];
#pragma unroll
    for (int kc = 0; kc < 2; ++kc)
#pragma unroll
        for (int k = 0; k < 4; ++k) {
            qw[kc][k] = ws[kc * 8 + k];
            qe[kc][k] = as[kc * 8 + k];
        }
    for (int kc = 0; kc < 2; ++kc) {
        {
            const int jb = half * 16;
#pragma unroll
            for (int k = 0; k < 4; ++k) {
                float4 q = qw[kc][k], e = qe[kc][k];
                sW[jb + 4*k + 0][pl] = q.x; sW[jb + 4*k + 1][pl] = q.y;
                sW[jb + 4*k + 2][pl] = q.z; sW[jb + 4*k + 3][pl] = q.w;
                sA[jb + 4*k + 0][pl] = e.x; sA[jb + 4*k + 1][pl] = e.y;
                sA[jb + 4*k + 2][pl] = e.z; sA[jb + 4*k + 3][pl] = e.w;
            }
        }
        __syncthreads();
#pragma unroll 4
        for (int j = 0; j < 32; ++j) {
            float4 a0 = *(const float4*)&sA[j][py];
            float4 a1 = *(const float4*)&sA[j][py + 4];
            float4 b0 = *(const float4*)&sW[j][ox];
            float4 b1 = *(const float4*)&sW[j][ox + 4];
            float av[8] = {a0.x,a0.y,a0.z,a0.w,a1.x,a1.y,a1.z,a1.w};
            float bv[8] = {b0.x,b0.y,b0.z,b0.w,b1.x,b1.y,b1.z,b1.w};
#pragma unroll
            for (int p = 0; p < 8; ++p)
#pragma unroll
                for (int o = 0; o < 8; ++o)
                    acc[p][o] = fmaf(av[p], bv[o], acc[p][o]);
        }
        __syncthreads();
    }
    float bo[8];
#pragma unroll
    for (int o = 0; o < 8; ++o) bo[o] = bih1[ox + o] + bhh1[ox + o];
#pragma unroll
    for (int p = 0; p < 8; ++p) {
        float* cp = pre1 + (size_t)(base + py + p) * HID + ox;
        *(float4*)cp       = make_float4(acc[p][0]+bo[0], acc[p][1]+bo[1], acc[p][2]+bo[2], acc[p][3]+bo[3]);
        *(float4*)(cp + 4) = make_float4(acc[p][4]+bo[4], acc[p][5]+bo[5], acc[p][6]+bo[6], acc[p][7]+bo[7]);
    }
}

// block-wide sum for 512 threads (8 waves); pass 0 from non-contributing lanes
__device__ inline float bsum512(float v, volatile float* sc, int tid) {
#pragma unroll
    for (int off = 32; off > 0; off >>= 1) v += __shfl_down(v, off, 64);
    __syncthreads();
    if ((tid & 63) == 0) sc[tid >> 6] = v;
    __syncthreads();
    float s = 0.f;
#pragma unroll
    for (int k = 0; k < 8; ++k) s += sc[k];
    return s;
}

// ---------------- kernel 2: fused two-layer recurrence, 8-wave low-DS form.
// 384 output rows = [Whh1@h1 (0-127) | Wih2@h1 -> P (128-255) | Whh2@h2 (256-383)],
// row R(w,j,rg) = w*48 + j*8 + rg  (j-major => h-source is wave-uniform per j).
// Wave classes: w<=4 read h1 only; w==5 reads both; w>=6 read h2 only.
// Per lane: 6 rows x 16 cols (96 fmaf, fp32); DPP butterfly reduce over e;
// writer lane (e<6) publishes row w*48 + e*8 + rg. Lag-1 pipeline (R6-proven):
//   h1[wp] = tanh(pre1[t] + Whh1@h1[rp]);  P[wp] = Wih2@h1[rp];
//   h2[wp] = tanh(b2 + P[rp] + Whh2@h2[rp])   (= h2_{t-2}).
// NO LDS staging: pre1 read per-step directly from global (2-step reg prefetch).
__global__ __launch_bounds__(512)
__attribute__((amdgpu_waves_per_eu(2)))
void k_rnn_fused(
    const float* __restrict__ pre1, const float* __restrict__ Whh1,
    const float* __restrict__ Wih2, const float* __restrict__ bih2,
    const float* __restrict__ bhh2, const float* __restrict__ Whh2,
    const float* __restrict__ ln_g, const float* __restrict__ ln_b,
    const float* __restrict__ projW, const float* __restrict__ proj_b,
    const float* __restrict__ on_g, const float* __restrict__ on_b,
    float* __restrict__ out)
{
    // h layout: value i at word (i>>4)*20 + (i&15); the 8 slices start at words
    // {0,20,...,140} == banks {0,20,8,28,16,4,24,12} -> conflict-free ds_read_b128.
    __shared__ __align__(16) float H1[2][160];
    __shared__ __align__(16) float H2[2][160];
    __shared__ __align__(16) float PP[2][HID];
    __shared__ float sfin[HID];
    __shared__ float xn[HID];
    __shared__ float sc[8];

    const int bb   = blockIdx.x;
    const int tid  = threadIdx.x;
    const int w    = tid >> 6, lane = tid & 63;
    const int e    = lane & 7;            // column-eighth: cols e*16 .. e*16+15
    const int rg   = lane >> 3;           // row-group 0..7
    const int cls  = (w < 5) ? 0 : ((w == 5) ? 1 : 2);

    // ---- 6 weight rows x 16 cols per lane (24 float4 = 96 floats)
    float4 W4[6][4];
#pragma unroll
    for (int j = 0; j < 6; ++j) {
        const int R = w * 48 + j * 8 + rg;
        const float* wp = (R < 128) ? (Whh1 + (size_t)R * HID)
                        : (R < 256) ? (Wih2 + (size_t)(R - 128) * HID)
                                    : (Whh2 + (size_t)(R - 256) * HID);
        const float4* wv = (const float4*)(wp + e * 16);
#pragma unroll
        for (int k = 0; k < 4; ++k) W4[j][k] = wv[k];
    }
#pragma unroll
    for (int j = 0; j < 6; ++j) { OPQ(W4[j][0]); OPQ(W4[j][1]); OPQ(W4[j][2]); OPQ(W4[j][3]); }

    // ---- writer role (lane e<6 publishes row Rw)
    const bool wr   = (e < 6);
    const int  Rw   = w * 48 + e * 8 + rg;
    const bool isH1 = wr && (Rw < 128);
    const bool isP  = wr && (Rw >= 128) && (Rw < 256);
    const bool isH2 = wr && (Rw >= 256);
    float* wpE; float* wpO;               // write ptr, even step (par 1) / odd (par 0)
    if (isH1)      { const int i0 = ((Rw >> 4) * 20) + (Rw & 15); wpE = &H1[1][i0]; wpO = &H1[0][i0]; }
    else if (isP)  { const int i0 = Rw - 128;                     wpE = &PP[1][i0]; wpO = &PP[0][i0]; }
    else if (isH2) { const int r2 = Rw - 256;
                     const int i0 = ((r2 >> 4) * 20) + (r2 & 15); wpE = &H2[1][i0]; wpO = &H2[0][i0]; }
    else           { wpE = &sc[0]; wpO = &sc[0]; }
    const float b2w = isH2 ? (bih2[Rw - 256] + bhh2[Rw - 256]) : 0.f;
    const float* prE = isH2 ? &PP[0][Rw - 256] : &PP[0][0];   // even step reads par 0
    const float* prO = isH2 ? &PP[1][Rw - 256] : &PP[1][0];

    // ---- h-slice read pointers (per parity, per source)
    const float4* hpE = (const float4*)(&H1[0][e * 20]);
    const float4* hpO = (const float4*)(&H1[1][e * 20]);
    const float4* gpE = (const float4*)(&H2[0][e * 20]);
    const float4* gpO = (const float4*)(&H2[1][e * 20]);

    if (tid < 160) { H1[0][tid] = 0.f; H1[1][tid] = 0.f; H2[0][tid] = 0.f; H2[1][tid] = 0.f; }
    if (tid < 128) { PP[0][tid] = 0.f; PP[1][tid] = 0.f; }

    const float* preblk = pre1 + (size_t)bb * 512 * HID;
    float pA = 0.f, pB = 0.f;
    if (isH1) { pA = preblk[Rw]; pB = preblk[HID + Rw]; }
    __syncthreads();

    auto stepf = [&](const float4* hp, const float4* gp, const float* pr,
                     float* wp, float& pslot, int tn, bool zeroH2, bool toSfin) {
        const float pv = pslot;
        float s0, s1, s2, s3, s4, s5;
        if (cls == 0) {
            float4 a0 = hp[0], a1 = hp[1], a2 = hp[2], a3 = hp[3];
            DOT16(s0, a0,a1,a2,a3, W4[0]); DOT16(s1, a0,a1,a2,a3, W4[1]);
            DOT16(s2, a0,a1,a2,a3, W4[2]); DOT16(s3, a0,a1,a2,a3, W4[3]);
            DOT16(s4, a0,a1,a2,a3, W4[4]); DOT16(s5, a0,a1,a2,a3, W4[5]);
        } else if (cls == 1) {
            float4 a0 = hp[0], a1 = hp[1], a2 = hp[2], a3 = hp[3];
            float4 g0 = gp[0], g1 = gp[1], g2 = gp[2], g3 = gp[3];
            DOT16(s0, a0,a1,a2,a3, W4[0]); DOT16(s1, a0,a1,a2,a3, W4[1]);
            DOT16(s2, g0,g1,g2,g3, W4[2]); DOT16(s3, g0,g1,g2,g3, W4[3]);
            DOT16(s4, g0,g1,g2,g3, W4[4]); DOT16(s5, g0,g1,g2,g3, W4[5]);
        } else {
            float4 g0 = gp[0], g1 = gp[1], g2 = gp[2], g3 = gp[3];
            DOT16(s0, g0,g1,g2,g3, W4[0]); DOT16(s1, g0,g1,g2,g3, W4[1]);
            DOT16(s2, g0,g1,g2,g3, W4[2]); DOT16(s3, g0,g1,g2,g3, W4[3]);
            DOT16(s4, g0,g1,g2,g3, W4[4]); DOT16(s5, g0,g1,g2,g3, W4[5]);
        }
        REDUCE6;
        float ta = (e & 1) ? s1 : s0;
        float tb = (e & 1) ? s3 : s2;
        float tc = (e & 1) ? s5 : s4;
        float u  = (e & 2) ? tb : ta;
        float v  = (e & 4) ? tc : u;
        float Prd = 0.f;
        if (isH2) Prd = *pr;
        const float add = isH1 ? pv : (isH2 ? (Prd + b2w) : 0.f);
        const float vf  = v + add;
        const float tv  = fast_tanh(vf);
        float res = isP ? vf : tv;
        if (zeroH2 && isH2) res = 0.f;
        if (isH1) pslot = preblk[(size_t)tn * HID + Rw];   // prefetch 2 steps ahead
        if (wr) {
            if (toSfin) { if (isH2) sfin[Rw - 256] = res; }
            else        *wp = res;
        }
        __syncthreads();
    };

    // t=0,1: h2 rows forced to 0 (h2_{-2}, h2_{-1})
    stepf(hpE, gpE, prE, wpE, pA, 2, true, false);
    stepf(hpO, gpO, prO, wpO, pB, 3, true, false);
#pragma unroll 1
    for (int t = 2; t < 512; t += 2) {
        stepf(hpE, gpE, prE, wpE, pA, (t + 2 < 512) ? t + 2 : 511, false, false);
        stepf(hpO, gpO, prO, wpO, pB, (t + 3 < 512) ? t + 3 : 511, false, false);
    }
    // drain: t=512 publishes P_512 & h2_510; t=513 computes h2_511 -> sfin
    stepf(hpE, gpE, prE, wpE, pA, 511, false, false);
    stepf(hpO, gpO, prO, wpO, pB, 511, false, true);

    // ---- epilogue: LN -> proj+tanh -> LN (R3-proven, 512-thread reductions)
    const int i = tid & 127;
    float hn = (tid < 128) ? sfin[i] : 0.f;
    float s1v = bsum512(hn, sc, tid);
    float s2v = bsum512(hn * hn, sc, tid);
    float mu  = s1v * (1.f / 128.f);
    float var = s2v * (1.f / 128.f) - mu * mu;
    __syncthreads();
    if (tid < 128) xn[i] = (hn - mu) * rsqrtf(var + 1e-5f) * ln_g[i] + ln_b[i];
    __syncthreads();
    float pvv = 0.f;
    if (tid < 128) {
        float a0 = proj_b[i], a1 = 0, a2 = 0, a3 = 0;
        const float4* hp = (const float4*)xn;
        const float4* pr = (const float4*)(projW + (size_t)i * HID);
#pragma unroll
        for (int k = 0; k < HID / 4; ++k) {
            float4 u = pr[k];
            float4 hv = hp[k];
            a0 = fmaf(hv.x, u.x, a0); a1 = fmaf(hv.y, u.y, a1);
            a2 = fmaf(hv.z, u.z, a2); a3 = fmaf(hv.w, u.w, a3);
        }
        pvv = tanhf((a0 + a1) + (a2 + a3));
    }
    float t1 = bsum512(pvv, sc, tid);
    float t2 = bsum512(pvv * pvv, sc, tid);
    float mu2  = t1 * (1.f / 128.f);
    float var2 = t2 * (1.f / 128.f) - mu2 * mu2;
    if (tid < 128)
        out[(size_t)bb * HID + i] = (pvv - mu2) * rsqrtf(var2 + 1e-5f) * on_g[i] + on_b[i];
}

extern "C" void kernel_launch(void* const* d_in, const int* in_sizes, int n_in,
                              void* d_out, int out_size, void* d_ws, size_t ws_size,
                              hipStream_t stream)
{
    const int*   x     = (const int*)  d_in[0];
    const float* emb   = (const float*)d_in[1];
    const float* Wih1  = (const float*)d_in[2];
    const float* bih1  = (const float*)d_in[3];
    const float* Whh1  = (const float*)d_in[4];
    const float* bhh1  = (const float*)d_in[5];
    const float* Wih2  = (const float*)d_in[6];
    const float* bih2  = (const float*)d_in[7];
    const float* Whh2  = (const float*)d_in[8];
    const float* bhh2  = (const float*)d_in[9];
    const float* ln_g  = (const float*)d_in[10];
    const float* ln_b  = (const float*)d_in[11];
    const float* projW = (const float*)d_in[12];
    const float* projb = (const float*)d_in[13];
    const float* on_g  = (const float*)d_in[14];
    const float* on_b  = (const float*)d_in[15];

    float* pre1 = (float*)d_ws;   // 64 MiB fp32

    k_embed_pre1<<<BT / 128, 256, 0, stream>>>(x, emb, Wih1, bih1, bhh1, pre1);
    k_rnn_fused<<<256, 512, 0, stream>>>(pre1, Whh1, Wih2, bih2, bhh2, Whh2,
                                         ln_g, ln_b, projW, projb, on_g, on_b,
                                         (float*)d_out);
}

// Round 9
// 433.625 us; speedup vs baseline: 2.9046x; 1.0867x over previous
//
#include <hip/hip_runtime.h>

#define HID 128
#define EMB 64
#define VOCAB 120000

__device__ __forceinline__ float fast_tanh(float x) {   // 1 - 2/(exp(2x)+1)
    float e = __expf(2.f * x);
    return 1.f - __fdividef(2.f, e + 1.f);
}

// pin a float4 (prevents rematerialization)
#define OPQ(v) asm volatile("" : "+v"(v.x), "+v"(v.y), "+v"(v.z), "+v"(v.w))

// ---- exact-codegen MAC: one VOP2 each (R3-proven)
#define FMAC(a, h, w) asm("v_fmac_f32 %0, %1, %2" : "+v"(a) : "v"(h), "v"(w))
#define VMUL(a, h, w) asm("v_mul_f32 %0, %1, %2" : "=v"(a) : "v"(h), "v"(w))
#define MAC4(hc, wa, wb, wcc, wd) \
    FMAC(s0, hc, wa); FMAC(s1, hc, wb); FMAC(s2, hc, wcc); FMAC(s3, hc, wd)

// ---- fused DPP butterfly reduce (R3-proven)
#define RED_STAGE(ctrl) \
    "v_add_f32_dpp %0, %0, %0 " ctrl " row_mask:0xf bank_mask:0xf\n\t" \
    "v_add_f32_dpp %1, %1, %1 " ctrl " row_mask:0xf bank_mask:0xf\n\t" \
    "v_add_f32_dpp %2, %2, %2 " ctrl " row_mask:0xf bank_mask:0xf\n\t" \
    "v_add_f32_dpp %3, %3, %3 " ctrl " row_mask:0xf bank_mask:0xf\n\t"
#define REDUCE_L1 asm("s_nop 1\n\t" \
    RED_STAGE("quad_perm:[1,0,3,2]") \
    RED_STAGE("quad_perm:[2,3,0,1]") \
    RED_STAGE("row_half_mirror") \
    : "+v"(s0), "+v"(s1), "+v"(s2), "+v"(s3))
#define REDUCE_L2 asm("s_nop 1\n\t" \
    RED_STAGE("quad_perm:[1,0,3,2]") \
    RED_STAGE("quad_perm:[2,3,0,1]") \
    RED_STAGE("row_half_mirror") \
    RED_STAGE("row_mirror") \
    : "+v"(s0), "+v"(s1), "+v"(s2), "+v"(s3))

// ---------------- kernel 1: W1E[v] = Wih1 @ emb[v] + bih1 + bhh1  (vocab-indexed
// fused embed+input-GEMM table; VOCAB=120000 rows < B*T=131072 rows k_embed did).
// Adapted from the proven k_embed_pre1 GEMM core; identity row ids, no gather.
__global__ __launch_bounds__(256)
__attribute__((amdgpu_waves_per_eu(1, 2)))
void k_w1e(
    const float* __restrict__ emb, const float* __restrict__ Wih1,
    const float* __restrict__ bih1, const float* __restrict__ bhh1,
    float* __restrict__ W1E)
{
    __shared__ float sA[32][128];
    __shared__ float sW[32][132];
    const int tid = threadIdx.x;
    const int base = blockIdx.x * 128;
    const int tx = tid & 15, ty = tid >> 4;
    const int ox = tx * 8, py = ty * 8;
    const int pl = tid & 127, half = tid >> 7;
    const int rv = min(base + pl, VOCAB - 1);   // clamped read row (tail block)
    float acc[8][8];
#pragma unroll
    for (int p = 0; p < 8; ++p)
#pragma unroll
        for (int o = 0; o < 8; ++o) acc[p][o] = 0.f;
    const float4* ws = (const float4*)(Wih1 + (size_t)pl * EMB + half * 16);
    const float4* as = (const float4*)(emb + (size_t)rv * EMB + half * 16);
    float4 qw[2][4], qe[2][4];
#pragma unroll
    for (int kc = 0; kc < 2; ++kc)
#pragma unroll
        for (int k = 0; k < 4; ++k) {
            qw[kc][k] = ws[kc * 8 + k];
            qe[kc][k] = as[kc * 8 + k];
        }
    for (int kc = 0; kc < 2; ++kc) {
        {
            const int jb = half * 16;
#pragma unroll
            for (int k = 0; k < 4; ++k) {
                float4 q = qw[kc][k], e = qe[kc][k];
                sW[jb + 4*k + 0][pl] = q.x; sW[jb + 4*k + 1][pl] = q.y;
                sW[jb + 4*k + 2][pl] = q.z; sW[jb + 4*k + 3][pl] = q.w;
                sA[jb + 4*k + 0][pl] = e.x; sA[jb + 4*k + 1][pl] = e.y;
                sA[jb + 4*k + 2][pl] = e.z; sA[jb + 4*k + 3][pl] = e.w;
            }
        }
        __syncthreads();
#pragma unroll 4
        for (int j = 0; j < 32; ++j) {
            float4 a0 = *(const float4*)&sA[j][py];
            float4 a1 = *(const float4*)&sA[j][py + 4];
            float4 b0 = *(const float4*)&sW[j][ox];
            float4 b1 = *(const float4*)&sW[j][ox + 4];
            float av[8] = {a0.x,a0.y,a0.z,a0.w,a1.x,a1.y,a1.z,a1.w};
            float bv[8] = {b0.x,b0.y,b0.z,b0.w,b1.x,b1.y,b1.z,b1.w};
#pragma unroll
            for (int p = 0; p < 8; ++p)
#pragma unroll
                for (int o = 0; o < 8; ++o)
                    acc[p][o] = fmaf(av[p], bv[o], acc[p][o]);
        }
        __syncthreads();
    }
    float bo[8];
#pragma unroll
    for (int o = 0; o < 8; ++o) bo[o] = bih1[ox + o] + bhh1[ox + o];
#pragma unroll
    for (int p = 0; p < 8; ++p) {
        const int vout = base + py + p;
        if (vout < VOCAB) {
            float* cp = W1E + (size_t)vout * HID + ox;
            *(float4*)cp       = make_float4(acc[p][0]+bo[0], acc[p][1]+bo[1], acc[p][2]+bo[2], acc[p][3]+bo[3]);
            *(float4*)(cp + 4) = make_float4(acc[p][4]+bo[4], acc[p][5]+bo[5], acc[p][6]+bo[6], acc[p][7]+bo[7]);
        }
    }
}

// block-wide sum for 768 threads (12 waves); pass 0 from non-contributing lanes
__device__ inline float bsum768(float v, volatile float* sc, int tid) {
#pragma unroll
    for (int off = 32; off > 0; off >>= 1) v += __shfl_down(v, off, 64);
    __syncthreads();
    if ((tid & 63) == 0) sc[tid >> 6] = v;
    __syncthreads();
    float s = 0.f;
#pragma unroll
    for (int k = 0; k < 12; ++k) s += sc[k];
    return s;
}

// ---------------- kernel 2: fused two-layer recurrence — R3-champion structure
// (347.7 µs measured), pre1 source swapped: per-step token gather from W1E
// (2-step register prefetch ring, R8-proven pattern) replaces LDS staging.
// waves 0-3 (L1): h1_t = tanh(W1E[tok[t]][r] + Whh1 @ h1_{t-1})
// waves 4-11(L2): h2_{t-1} = tanh(b2 + Wih2@h1_{t-1} + Whh2@h2_{t-2})  (lag-1)
__global__ __launch_bounds__(768)
__attribute__((amdgpu_waves_per_eu(3)))
void k_rnn_fused(
    const int* __restrict__ x, const float* __restrict__ W1E,
    const float* __restrict__ Whh1,
    const float* __restrict__ Wih2, const float* __restrict__ bih2,
    const float* __restrict__ bhh2, const float* __restrict__ Whh2,
    const float* __restrict__ ln_g, const float* __restrict__ ln_b,
    const float* __restrict__ projW, const float* __restrict__ proj_b,
    const float* __restrict__ on_g, const float* __restrict__ on_b,
    float* __restrict__ out)
{
    // h layout: value i at word (i>>4)*20 + (i&15) -> conflict-free ds_read_b128.
    __shared__ __align__(16) float h1[2][160];
    __shared__ __align__(16) float h2[2][160];
    __shared__ int   tok[512];
    __shared__ float sfin[HID];
    __shared__ float xn[HID];
    __shared__ float sc[12];

    const int bb   = blockIdx.x;
    const int tid  = threadIdx.x;
    const int w    = tid >> 6;
    const int lane = tid & 63;
    const bool L1  = (w < 4);
    const int  e   = lane & 7;                     // column-eighth
    const int  m   = L1 ? 0 : ((lane >> 3) & 1);   // L2: 0 = Wih2 (h1), 1 = Whh2 (h2)
    const int  rg  = L1 ? (lane >> 3) : (lane >> 4);
    const int  rowbase = L1 ? (32 * w + rg) : (16 * (w - 4) + rg);
    const int  rstep   = L1 ? 8 : 4;
    const float* wmat  = L1 ? Whh1 : (m ? Whh2 : Wih2);

    // ---- 4 rows x 16 cols of weights (16 float4 = 64 floats / lane)
    const float4* wr0 = (const float4*)(wmat + (size_t)(rowbase            ) * HID + e * 16);
    const float4* wr1 = (const float4*)(wmat + (size_t)(rowbase +     rstep) * HID + e * 16);
    const float4* wr2 = (const float4*)(wmat + (size_t)(rowbase + 2 * rstep) * HID + e * 16);
    const float4* wr3 = (const float4*)(wmat + (size_t)(rowbase + 3 * rstep) * HID + e * 16);
    float4 w0 = wr0[0], w1 = wr0[1], w2  = wr0[2], w3  = wr0[3],
           w4 = wr1[0], w5 = wr1[1], w6  = wr1[2], w7  = wr1[3],
           w8 = wr2[0], w9 = wr2[1], w10 = wr2[2], w11 = wr2[3],
           w12= wr3[0], w13= wr3[1], w14 = wr3[2], w15 = wr3[3];
    OPQ(w0);OPQ(w1);OPQ(w2);OPQ(w3);OPQ(w4);OPQ(w5);OPQ(w6);OPQ(w7);
    OPQ(w8);OPQ(w9);OPQ(w10);OPQ(w11);OPQ(w12);OPQ(w13);OPQ(w14);OPQ(w15);

    // publisher role: lanes e<4 (for L2 only m==0 half) write row rowbase+(e&3)*rstep
    const bool wr_en = L1 ? (e < 4) : (m == 0 && e < 4);
    const int  wrow  = rowbase + (e & 3) * rstep;
    const int  wword = ((wrow >> 4) * 20) + (wrow & 15);
    const float b2w  = (!L1 && wr_en) ? (bih2[wrow] + bhh2[wrow]) : 0.f;
    const bool pfe   = L1 && wr_en;                // this lane gathers pre values

    if (tid < 160) { h1[0][tid] = 0.f; h2[0][tid] = 0.f; }
    if (tid < 512) tok[tid] = x[bb * 512 + tid];

    // parity-resolved pointers (even t reads [0] writes [1]; odd t flips)
    const float* srcb = (L1 || m == 0) ? &h1[0][0] : &h2[0][0];
    const float4* rp0 = (const float4*)(srcb + e * 20);
    const float4* rp1 = (const float4*)(srcb + 160 + e * 20);
    float* dstb = L1 ? &h1[0][0] : &h2[0][0];
    float* wp_e = dstb + 160 + wword;   // even step writes parity 1
    float* wp_o = dstb + wword;         // odd step writes parity 0

    __syncthreads();                    // h init + tok visible

    // pre-value register ring (2-step prefetch): pA even steps, pB odd steps
    float pA = 0.f, pB = 0.f;
    if (pfe) {
        pA = W1E[(size_t)tok[0] * HID + wrow];
        pB = W1E[(size_t)tok[1] * HID + wrow];
    }

    auto do_step = [&](int t, float& pslot, int tn, const float4* rp, float* wpt) {
        const float pv = pslot;
        float4 hv0 = rp[0], hv1 = rp[1], hv2 = rp[2], hv3 = rp[3];
        float s0, s1, s2, s3;
        VMUL(s0, hv0.x, w0.x); VMUL(s1, hv0.x, w4.x);
        VMUL(s2, hv0.x, w8.x); VMUL(s3, hv0.x, w12.x);
        MAC4(hv0.y, w0.y, w4.y, w8.y, w12.y);
        MAC4(hv0.z, w0.z, w4.z, w8.z, w12.z);
        MAC4(hv0.w, w0.w, w4.w, w8.w, w12.w);
        MAC4(hv1.x, w1.x, w5.x, w9.x, w13.x);
        MAC4(hv1.y, w1.y, w5.y, w9.y, w13.y);
        MAC4(hv1.z, w1.z, w5.z, w9.z, w13.z);
        MAC4(hv1.w, w1.w, w5.w, w9.w, w13.w);
        MAC4(hv2.x, w2.x, w6.x, w10.x, w14.x);
        MAC4(hv2.y, w2.y, w6.y, w10.y, w14.y);
        MAC4(hv2.z, w2.z, w6.z, w10.z, w14.z);
        MAC4(hv2.w, w2.w, w6.w, w10.w, w14.w);
        MAC4(hv3.x, w3.x, w7.x, w11.x, w15.x);
        MAC4(hv3.y, w3.y, w7.y, w11.y, w15.y);
        MAC4(hv3.z, w3.z, w7.z, w11.z, w15.z);
        MAC4(hv3.w, w3.w, w7.w, w11.w, w15.w);
        if (L1) { REDUCE_L1; } else { REDUCE_L2; }
        if (pfe) pslot = W1E[(size_t)tok[tn] * HID + wrow];   // prefetch 2 ahead
        if (wr_en) {
            float ta = (e & 1) ? s1 : s0;
            float tb = (e & 1) ? s3 : s2;
            float v  = (e & 2) ? tb : ta;
            if (L1) *wpt = fast_tanh(pv + v);
            else    *wpt = (t > 0) ? fast_tanh(b2w + v) : 0.f;   // h2_{-1} = 0
        }
        __syncthreads();
    };

#pragma unroll 1
    for (int t = 0; t < 512; t += 2) {
        do_step(t,     pA, (t + 2 < 512) ? t + 2 : 511, rp0, wp_e);
        do_step(t + 1, pB, (t + 3 < 512) ? t + 3 : 511, rp1, wp_o);
    }

    // drain: h2_511 = tanh(b2 + Wih2@h1_511 + Whh2@h2_510); both live at parity 0.
    // L1 lanes compute a dead value into h1[1] (harmless).
    {
        float* wpD = L1 ? wp_e : &sfin[wrow];
        do_step(512, pA, 511, rp0, wpD);
    }

    // ---- epilogue: LN -> proj+tanh -> LN (R3-proven)
    const int i = tid & 127;
    float hn = (tid < 128) ? sfin[i] : 0.f;
    float s1v = bsum768(hn, sc, tid);
    float s2v = bsum768(hn * hn, sc, tid);
    float mu = s1v * (1.f / 128.f);
    float var = s2v * (1.f / 128.f) - mu * mu;
    __syncthreads();
    if (tid < 128) xn[i] = (hn - mu) * rsqrtf(var + 1e-5f) * ln_g[i] + ln_b[i];
    __syncthreads();
    float pv = 0.f;
    if (tid < 128) {
        float a0 = proj_b[i], a1 = 0, a2 = 0, a3 = 0;
        const float4* hp = (const float4*)xn;
        const float4* pr = (const float4*)(projW + (size_t)i * HID);
#pragma unroll
        for (int k = 0; k < HID / 4; ++k) {
            float4 u = pr[k];
            float4 hv = hp[k];
            a0 = fmaf(hv.x, u.x, a0); a1 = fmaf(hv.y, u.y, a1);
            a2 = fmaf(hv.z, u.z, a2); a3 = fmaf(hv.w, u.w, a3);
        }
        pv = tanhf((a0 + a1) + (a2 + a3));
    }
    float t1 = bsum768(pv, sc, tid);
    float t2 = bsum768(pv * pv, sc, tid);
    float mu2 = t1 * (1.f / 128.f);
    float var2 = t2 * (1.f / 128.f) - mu2 * mu2;
    if (tid < 128)
        out[(size_t)bb * HID + i] = (pv - mu2) * rsqrtf(var2 + 1e-5f) * on_g[i] + on_b[i];
}

extern "C" void kernel_launch(void* const* d_in, const int* in_sizes, int n_in,
                              void* d_out, int out_size, void* d_ws, size_t ws_size,
                              hipStream_t stream)
{
    const int*   x     = (const int*)  d_in[0];
    const float* emb   = (const float*)d_in[1];
    const float* Wih1  = (const float*)d_in[2];
    const float* bih1  = (const float*)d_in[3];
    const float* Whh1  = (const float*)d_in[4];
    const float* bhh1  = (const float*)d_in[5];
    const float* Wih2  = (const float*)d_in[6];
    const float* bih2  = (const float*)d_in[7];
    const float* Whh2  = (const float*)d_in[8];
    const float* bhh2  = (const float*)d_in[9];
    const float* ln_g  = (const float*)d_in[10];
    const float* ln_b  = (const float*)d_in[11];
    const float* projW = (const float*)d_in[12];
    const float* projb = (const float*)d_in[13];
    const float* on_g  = (const float*)d_in[14];
    const float* on_b  = (const float*)d_in[15];

    float* W1E = (float*)d_ws;   // [VOCAB][128] fp32 = 61.4 MB (ws is 64 MiB)

    k_w1e<<<(VOCAB + 127) / 128, 256, 0, stream>>>(emb, Wih1, bih1, bhh1, W1E);
    k_rnn_fused<<<256, 768, 0, stream>>>(x, W1E, Whh1, Wih2, bih2, bhh2, Whh2,
                                         ln_g, ln_b, projW, projb, on_g, on_b,
                                         (float*)d_out);
}